// Round 10
// baseline (288.108 us; speedup 1.0000x reference)
//
#include <hip/hip_runtime.h>

// 2-layer LSTM, B=4096, T=168, D=16, H1=64, H2=32, fp32 in/out.
// R10: R9 + x-projection offload. The four L2 waves compute
// xg(t+1) = W_ih1.x(t+1) + b1 (4 tiles x 2 exact packed-cross MFMAs each)
// into ping-pong LDS sXG one interval ahead; L1 seeds its MFMA accumulators
// straight from sXG (f32x4 ds_read as C-input). Removes from the L1 waves:
// 8/32 MFMAs, the x hi/lo split VALU, bias-init movs, global-load logic --
// rebalancing VALU (R9: trans-heavy L1/L2b vs idle L2a) without changing
// per-SIMD MFMA totals (44/56).
// Roles (512 thr/block, grid 256, 1 block/CU, 2 waves/SIMD):
//   w0-3 : h1(t) = LSTM1(h1(t-1)) + xg(t)            [24 MFMA]
//   w6,7 : pA(t-1) = full W_ih2 . h1(t-1)            [24 MFMA] + xg(t+1) [8]
//   w4,5 : h2(t-2) = act(pA(t-2) + W_hh2 . h2(t-3))  [12 MFMA] + xg(t+1) [8]
// mfma_f32_16x16x32_bf16 hi/lo split, lo*lo dropped (validated: absmax 6.1e-5).

typedef __bf16 bf16x8 __attribute__((ext_vector_type(8)));
typedef float  f32x4  __attribute__((ext_vector_type(4)));

constexpr int T_SEQ = 168;
constexpr int NB    = 16;

__device__ __forceinline__ float fsig(float v)  { return __builtin_amdgcn_rcpf(1.f + __expf(-v)); }
__device__ __forceinline__ float ftanhf(float v){ return 2.f * __builtin_amdgcn_rcpf(1.f + __expf(-2.f * v)) - 1.f; }

__device__ __forceinline__ void split_bf16(float x, __bf16& hi, __bf16& lo) {
  hi = (__bf16)x;
  lo = (__bf16)(x - (float)hi);
}

__device__ __forceinline__ void load_frag8(const float* __restrict__ Wrow, int k0,
                                           bf16x8& hi, bf16x8& lo) {
#pragma unroll
  for (int j = 0; j < 8; ++j) {
    float v = Wrow[k0 + j];
    __bf16 h = (__bf16)v;
    hi[j] = h;
    lo[j] = (__bf16)(v - (float)h);
  }
}

#define MFMA(a, b, c) __builtin_amdgcn_mfma_f32_16x16x32_bf16((a), (b), (c), 0, 0, 0)

__global__ __launch_bounds__(512) __attribute__((amdgpu_waves_per_eu(2, 2)))
void lstm_mfma_kernel(const float* __restrict__ x,
    const float* __restrict__ Wih1, const float* __restrict__ Whh1,
    const float* __restrict__ bih1, const float* __restrict__ bhh1,
    const float* __restrict__ Wih2, const float* __restrict__ Whh2,
    const float* __restrict__ bih2, const float* __restrict__ bhh2,
    const float* __restrict__ Wfc,  const float* __restrict__ bfc,
    float* __restrict__ out)
{
  __shared__ __align__(16) __bf16 sA1[2][4 * 64 * 8];      // h1 hi(kb0,1)/lo(kb2,3) (8 KB)
  __shared__ __align__(16) __bf16 sA2[2][2 * 64 * 8];      // h2 hi(kb0)/lo(kb1) (4 KB)
  __shared__ __align__(16) __bf16 sW2lo[8 * 2 * 64 * 8];   // W_ih2 LO frags (16 KB)
  __shared__ __align__(16) float  sP[2][2 * 4 * 64 * 4];   // pA partials, ping-pong (16 KB)
  __shared__ __align__(16) float  sXG[2][16 * 64 * 4];     // xg pre-acts, ping-pong (32 KB)
  __shared__ __align__(16) float  sH2f[16 * 32];           // final h2 [batch][unit]

  const int tid  = threadIdx.x;
  const int w    = tid >> 6;        // wave 0..7
  const int lane = tid & 63;
  const int q    = lane >> 4;
  const int col  = lane & 15;
  const int b0   = blockIdx.x * NB;

  const bool isL1  = (w < 4);
  const bool isL2  = (w >= 4);
  const bool isL2b = (w == 4) || (w == 5);
  const bool isL2a = (w >= 6);
  const int  wl2b  = w - 4;
  const int  wl2a  = w - 6;
  const int  tbase = (w - 4) * 4;   // xg tile range for L2 waves

  // ---------------- L1 weights into registers: W_hh1 only ----------------
  bf16x8 bhh[4][4];   // hi(kb0,1)/lo(kb2,3)
  if (isL1) {
#pragma unroll
    for (int g = 0; g < 4; ++g) {
      const int r = g * 64 + w * 16 + col;
      const float* Wr = Whh1 + r * 64;
      bf16x8 h0, l0, h1f, l1f;
      load_frag8(Wr, 0 * 32 + q * 8, h0, l0);
      load_frag8(Wr, 1 * 32 + q * 8, h1f, l1f);
      bhh[g][0] = h0; bhh[g][1] = h1f; bhh[g][2] = l0; bhh[g][3] = l1f;
    }
  }
  // ---------------- L2b weights: W_hh2 hi/lo ----------------
  bf16x8 wh2h[4], wh2l[4];
  float  b2v[4] = {0.f, 0.f, 0.f, 0.f};
  if (isL2b) {
#pragma unroll
    for (int g = 0; g < 4; ++g) {
      const int r = g * 32 + wl2b * 16 + col;
      bf16x8 hh, ll;
      load_frag8(Whh2 + r * 32, q * 8, hh, ll);
      wh2h[g] = hh; wh2l[g] = ll;
      b2v[g] = bih2[r] + bhh2[r];
    }
  }
  // ---------------- L2a weights: W_ih2 HI ----------------
  bf16x8 w2ih[4][2];
  if (isL2a) {
#pragma unroll
    for (int g = 0; g < 4; ++g) {
      const int r = g * 32 + wl2a * 16 + col;
#pragma unroll
      for (int kb = 0; kb < 2; ++kb) {
        bf16x8 hh, ll;
        load_frag8(Wih2 + r * 64, kb * 32 + q * 8, hh, ll);
        w2ih[g][kb] = hh;
      }
    }
  }
  // ---------------- L2 (all 4): W_ih1 packed [Wh;Wl] + bias for xg tiles ----------------
  bf16x8 wxg[4];
  float  bxg[4] = {0.f, 0.f, 0.f, 0.f};
  if (isL2) {
#pragma unroll
    for (int i = 0; i < 4; ++i) {
      const int row = (tbase + i) * 16 + col;
      bf16x8 hh, ll;
      load_frag8(Wih1 + row * 16, (q & 1) * 8, hh, ll);
      wxg[i] = (q < 2) ? hh : ll;
      bxg[i] = bih1[row] + bhh1[row];
    }
  }

  // ---------------- LDS staging: W_ih2 LO frags ----------------
  for (int idx = tid; idx < 8 * 2 * 64; idx += 512) {
    const int nt  = idx >> 7;
    const int kb2 = (idx >> 6) & 1;
    const int ln  = idx & 63;
    const int qq  = ln >> 4, cc = ln & 15;
    const int g   = nt >> 1, wv = nt & 1;
    const int r   = g * 32 + wv * 16 + cc;
    const int k0  = kb2 * 32 + qq * 8;
    bf16x8 hh, ll;
    load_frag8(Wih2 + r * 64, k0, hh, ll);
    *(bf16x8*)&sW2lo[((nt * 2 + kb2) * 64 + ln) * 8] = ll;
  }

  // ---------------- zero state buffers ----------------
  {
    bf16x8 z;
#pragma unroll
    for (int j = 0; j < 8; ++j) z[j] = (__bf16)0.f;
    for (int i = tid; i < 2 * 4 * 64; i += 512) *(bf16x8*)&sA1[0][i * 8] = z;
    for (int i = tid; i < 2 * 2 * 64; i += 512) *(bf16x8*)&sA2[0][i * 8] = z;
  }

  // ---------------- xg(0) into sXG[0] + prefetch x(1) (L2 waves) ----------------
  const float* xbase = x + ((size_t)(b0 + col) * T_SEQ) * 16 + (q & 1) * 8;
  float4 xcA, xcB, xnA, xnB;
  if (isL2) {
    xcA = *(const float4*)(xbase + 0);
    xcB = *(const float4*)(xbase + 4);
    const float xcv[8] = {xcA.x, xcA.y, xcA.z, xcA.w, xcB.x, xcB.y, xcB.z, xcB.w};
    bf16x8 xh8, xl8;
#pragma unroll
    for (int j = 0; j < 8; ++j) {
      __bf16 h_, l_; split_bf16(xcv[j], h_, l_);
      xh8[j] = h_; xl8[j] = l_;
    }
    const bf16x8 ax0 = (q < 2) ? xh8 : xl8;
    const bf16x8 ax1 = (q < 2) ? xl8 : xh8;
#pragma unroll
    for (int i = 0; i < 4; ++i) {
      f32x4 cx;
      cx[0] = bxg[i]; cx[1] = bxg[i]; cx[2] = bxg[i]; cx[3] = bxg[i];
      cx = MFMA(ax0, wxg[i], cx);
      cx = MFMA(ax1, wxg[i], cx);
      *(f32x4*)&sXG[0][(((tbase + i) * 64) + lane) * 4] = cx;
    }
    xcA = *(const float4*)(xbase + 16);   // x(1)
    xcB = *(const float4*)(xbase + 20);
  }
  __syncthreads();

  float c1s[4] = {0.f, 0.f, 0.f, 0.f};
  float c2s[4] = {0.f, 0.f, 0.f, 0.f};
  const int uu   = w * 16 + col;      // L1 unit
  const int uu2b = wl2b * 16 + col;   // L2b unit

  const int kbh  = uu >> 5;
  const int lnb  = ((uu & 31) >> 3) * 16;
  const int jj   = uu & 7;
  const int lnb2 = ((uu2b & 31) >> 3) * 16;
  const int jj2  = uu2b & 7;

  const f32x4 z4 = {0.f, 0.f, 0.f, 0.f};

// One pipeline interval. Pc and DO_* are compile-time literals.
#define STEP(Pc, DO_L1, DO_XPRE, DO_XG, DO_L2A, DO_L2B, DO_H2F, TT) do {       \
    if ((DO_L1) && isL1) {                                                     \
      bf16x8 a1[4];                                                            \
      _Pragma("unroll")                                                        \
      for (int kb = 0; kb < 4; ++kb)                                           \
        a1[kb] = *(const bf16x8*)&sA1[(Pc)][(kb * 64 + lane) * 8];             \
      f32x4 xg[4];                                                             \
      _Pragma("unroll")                                                        \
      for (int g = 0; g < 4; ++g)                                              \
        xg[g] = *(const f32x4*)&sXG[(Pc)][(((g * 4 + w) * 64) + lane) * 4];    \
      f32x4 ca[4], cb[4];                                                      \
      _Pragma("unroll")                                                        \
      for (int g = 0; g < 4; ++g) {                                            \
        ca[g] = MFMA(a1[0], bhh[g][0], xg[g]);  /* hi x hi kb0 */              \
        ca[g] = MFMA(a1[1], bhh[g][1], ca[g]);  /* hi x hi kb1 */              \
        ca[g] = MFMA(a1[2], bhh[g][0], ca[g]);  /* lo x hi kb0 */              \
        cb[g] = MFMA(a1[3], bhh[g][1], z4);     /* lo x hi kb1 */              \
        cb[g] = MFMA(a1[0], bhh[g][2], cb[g]);  /* hi x lo kb0 */              \
        cb[g] = MFMA(a1[1], bhh[g][3], cb[g]);  /* hi x lo kb1 */              \
      }                                                                        \
      _Pragma("unroll")                                                        \
      for (int r = 0; r < 4; ++r) {                                            \
        const float iv = fsig(ca[0][r] + cb[0][r]);                            \
        const float fv = fsig(ca[1][r] + cb[1][r]);                            \
        const float gv = ftanhf(ca[2][r] + cb[2][r]);                          \
        const float ov = fsig(ca[3][r] + cb[3][r]);                            \
        const float cc = fmaf(fv, c1s[r], iv * gv);                            \
        c1s[r] = cc;                                                           \
        __bf16 hh_, hl_;                                                       \
        split_bf16(ov * ftanhf(cc), hh_, hl_);                                 \
        const int m = q * 4 + r;                                               \
        sA1[1 - (Pc)][((kbh * 64) + lnb + m) * 8 + jj]       = hh_;            \
        sA1[1 - (Pc)][(((2 + kbh) * 64) + lnb + m) * 8 + jj] = hl_;            \
      }                                                                        \
    }                                                                          \
    if ((DO_L2A) && isL2a) {                                                   \
      bf16x8 a2[4];                                                            \
      _Pragma("unroll")                                                        \
      for (int kb = 0; kb < 4; ++kb)                                           \
        a2[kb] = *(const bf16x8*)&sA1[(Pc)][(kb * 64 + lane) * 8];             \
      _Pragma("unroll")                                                        \
      for (int g = 0; g < 4; ++g) {                                            \
        const int nt = g * 2 + wl2a;                                           \
        const bf16x8 bb2 = *(const bf16x8*)&sW2lo[((nt * 2 + 0) * 64 + lane) * 8]; \
        const bf16x8 bb3 = *(const bf16x8*)&sW2lo[((nt * 2 + 1) * 64 + lane) * 8]; \
        f32x4 pa = {0.f, 0.f, 0.f, 0.f};                                       \
        pa = MFMA(a2[0], w2ih[g][0], pa);   /* hi x hi */                      \
        pa = MFMA(a2[1], w2ih[g][1], pa);                                      \
        pa = MFMA(a2[0], bb2, pa);          /* hi x lo */                      \
        pa = MFMA(a2[1], bb3, pa);                                             \
        pa = MFMA(a2[2], w2ih[g][0], pa);   /* lo x hi */                      \
        pa = MFMA(a2[3], w2ih[g][1], pa);                                      \
        *(f32x4*)&sP[(Pc)][((wl2a * 4 + g) * 64 + lane) * 4] = pa;             \
      }                                                                        \
    }                                                                          \
    if ((DO_L2B) && isL2b) {                                                   \
      const bf16x8 ah0 = *(const bf16x8*)&sA2[1 - (Pc)][(0 * 64 + lane) * 8];  \
      const bf16x8 ah1 = *(const bf16x8*)&sA2[1 - (Pc)][(1 * 64 + lane) * 8];  \
      f32x4 c2[4];                                                             \
      _Pragma("unroll")                                                        \
      for (int g = 0; g < 4; ++g) {                                            \
        c2[g][0] = b2v[g]; c2[g][1] = b2v[g]; c2[g][2] = b2v[g]; c2[g][3] = b2v[g]; \
        c2[g] = MFMA(ah0, wh2h[g], c2[g]);                                     \
        c2[g] = MFMA(ah1, wh2h[g], c2[g]);                                     \
        c2[g] = MFMA(ah0, wh2l[g], c2[g]);                                     \
        c2[g] += *(const f32x4*)&sP[1 - (Pc)][((wl2b * 4 + g) * 64 + lane) * 4]; \
      }                                                                        \
      _Pragma("unroll")                                                        \
      for (int r = 0; r < 4; ++r) {                                            \
        const float iv = fsig(c2[0][r]);                                       \
        const float fv = fsig(c2[1][r]);                                       \
        const float gv = ftanhf(c2[2][r]);                                     \
        const float ov = fsig(c2[3][r]);                                       \
        const float cc = fmaf(fv, c2s[r], iv * gv);                            \
        c2s[r] = cc;                                                           \
        const float hf = ov * ftanhf(cc);                                      \
        __bf16 hh_, hl_;                                                       \
        split_bf16(hf, hh_, hl_);                                              \
        const int m = q * 4 + r;                                               \
        sA2[(Pc)][((0 * 64) + lnb2 + m) * 8 + jj2] = hh_;                      \
        sA2[(Pc)][((1 * 64) + lnb2 + m) * 8 + jj2] = hl_;                      \
        if (DO_H2F) sH2f[m * 32 + uu2b] = hf;                                  \
      }                                                                        \
    }                                                                          \
    if ((DO_XG) && isL2) {  /* xg(TT+1) from xc regs (x(TT+1)) */              \
      if (DO_XPRE) {                                                           \
        const float* xr = xbase + (size_t)((TT) + 2) * 16;                     \
        xnA = *(const float4*)(xr + 0);                                        \
        xnB = *(const float4*)(xr + 4);                                        \
      }                                                                        \
      const float xcv[8] = {xcA.x, xcA.y, xcA.z, xcA.w, xcB.x, xcB.y, xcB.z, xcB.w}; \
      bf16x8 xh8, xl8;                                                         \
      _Pragma("unroll")                                                        \
      for (int j = 0; j < 8; ++j) {                                            \
        __bf16 h_, l_; split_bf16(xcv[j], h_, l_);                             \
        xh8[j] = h_; xl8[j] = l_;                                              \
      }                                                                        \
      const bf16x8 ax0 = (q < 2) ? xh8 : xl8;                                  \
      const bf16x8 ax1 = (q < 2) ? xl8 : xh8;                                  \
      _Pragma("unroll")                                                        \
      for (int i = 0; i < 4; ++i) {                                            \
        f32x4 cx;                                                              \
        cx[0] = bxg[i]; cx[1] = bxg[i]; cx[2] = bxg[i]; cx[3] = bxg[i];        \
        cx = MFMA(ax0, wxg[i], cx);                                            \
        cx = MFMA(ax1, wxg[i], cx);                                            \
        *(f32x4*)&sXG[1 - (Pc)][(((tbase + i) * 64) + lane) * 4] = cx;         \
      }                                                                        \
      if (DO_XPRE) { xcA = xnA; xcB = xnB; }                                   \
    }                                                                          \
    __syncthreads();                                                           \
  } while (0)

  // -------- pipeline fill --------
  STEP(0, true,  true,  true,  false, false, false, 0);
  STEP(1, true,  true,  true,  true,  false, false, 1);
  // -------- steady state --------
  for (int t = 2; t < 166; t += 2) {
    STEP(0, true, true, true, true, true, false, t);
    STEP(1, true, true, true, true, true, false, t + 1);
  }
  // -------- drain --------
  STEP(0, true,  false, true,  true,  true,  false, 166);  // xg(167) from xc
  STEP(1, true,  false, false, true,  true,  false, 167);  // last L1 step
  STEP(0, false, false, false, true,  true,  false, 168);  // pA(167), h2(166)
  STEP(1, false, false, false, false, true,  true,  169);  // h2(167) + store
#undef STEP

  // ======== FC epilogue ========
  if (tid < NB) {
    float s = bfc[0];
#pragma unroll
    for (int j = 0; j < 32; ++j) s = fmaf(Wfc[j], sH2f[tid * 32 + j], s);
    out[b0 + tid] = s;
  }
}

extern "C" void kernel_launch(void* const* d_in, const int* in_sizes, int n_in,
                              void* d_out, int out_size, void* d_ws, size_t ws_size,
                              hipStream_t stream) {
  (void)in_sizes; (void)n_in; (void)out_size; (void)d_ws; (void)ws_size;
  const float* x    = (const float*)d_in[0];
  const float* Wih1 = (const float*)d_in[1];
  const float* Whh1 = (const float*)d_in[2];
  const float* bih1 = (const float*)d_in[3];
  const float* bhh1 = (const float*)d_in[4];
  const float* Wih2 = (const float*)d_in[5];
  const float* Whh2 = (const float*)d_in[6];
  const float* bih2 = (const float*)d_in[7];
  const float* bhh2 = (const float*)d_in[8];
  const float* Wfc  = (const float*)d_in[9];
  const float* bfc  = (const float*)d_in[10];
  float* out = (float*)d_out;

  hipLaunchKernelGGL(lstm_mfma_kernel, dim3(4096 / NB), dim3(512), 0, stream,
                     x, Wih1, Whh1, bih1, bhh1, Wih2, Whh2, bih2, bhh2, Wfc, bfc, out);
}

// Round 11
// 270.401 us; speedup vs baseline: 1.0655x; 1.0655x over previous
//
#include <hip/hip_runtime.h>

// 2-layer LSTM, B=4096, T=168, D=16, H1=64, H2=32, fp32 in/out.
// R11 = R9 (best, 215us dispatch) + VALU-issue reduction:
//  - integer truncation bf16 splits (and/sub/shr) replace rne (__bf16) casts
//    in the hot loop (compiler rne sequences were the VALU-pipe excess)
//  - s_setprio(1) on L1 waves (serial-chain wins SIMD issue arbitration)
//  - hoisted f32x4 bias seeds + z4-seeded cb chains (kill per-step movs)
// Roles (512 thr/block, grid 256, 1 block/CU, 2 waves/SIMD):
//   w0-3 : h1(t)   = LSTM1(h1(t-1), x(t))            [32 MFMA, lo*lo dropped]
//   w6,7 : pA(t-1) = full W_ih2 . h1(t-1)            [24 MFMA]
//   w4,5 : h2(t-2) = act(pA(t-2) + W_hh2 . h2(t-3))  [12 MFMA, self-recurrent]
// mfma_f32_16x16x32_bf16 hi/lo split, lo*lo dropped.

typedef __bf16 bf16x8 __attribute__((ext_vector_type(8)));
typedef float  f32x4  __attribute__((ext_vector_type(4)));

constexpr int T_SEQ = 168;
constexpr int NB    = 16;

__device__ __forceinline__ float fsig(float v)  { return __builtin_amdgcn_rcpf(1.f + __expf(-v)); }
__device__ __forceinline__ float ftanhf(float v){ return 2.f * __builtin_amdgcn_rcpf(1.f + __expf(-2.f * v)) - 1.f; }

// rne split (init-time only, off the hot loop)
__device__ __forceinline__ void split_bf16(float x, __bf16& hi, __bf16& lo) {
  hi = (__bf16)x;
  lo = (__bf16)(x - (float)hi);
}

// hot-loop split: pure integer ops. hi = trunc-to-bf16(x) (error captured
// EXACTLY in lo since x - trunc16(x) has <=16 significant bits); lo truncated
// (residual error ~2^-16 relative). ~4 VALU vs rne's multi-instr sequence.
__device__ __forceinline__ void split_fast(float x, __bf16& hi, __bf16& lo) {
  const unsigned u  = __float_as_uint(x);
  const unsigned hb = u & 0xFFFF0000u;
  const float    lf = x - __uint_as_float(hb);
  hi = __builtin_bit_cast(__bf16, (unsigned short)(hb >> 16));
  lo = __builtin_bit_cast(__bf16, (unsigned short)(__float_as_uint(lf) >> 16));
}

__device__ __forceinline__ void load_frag8(const float* __restrict__ Wrow, int k0,
                                           bf16x8& hi, bf16x8& lo) {
#pragma unroll
  for (int j = 0; j < 8; ++j) {
    float v = Wrow[k0 + j];
    __bf16 h = (__bf16)v;
    hi[j] = h;
    lo[j] = (__bf16)(v - (float)h);
  }
}

#define MFMA(a, b, c) __builtin_amdgcn_mfma_f32_16x16x32_bf16((a), (b), (c), 0, 0, 0)

__global__ __launch_bounds__(512) __attribute__((amdgpu_waves_per_eu(2, 2)))
void lstm_mfma_kernel(const float* __restrict__ x,
    const float* __restrict__ Wih1, const float* __restrict__ Whh1,
    const float* __restrict__ bih1, const float* __restrict__ bhh1,
    const float* __restrict__ Wih2, const float* __restrict__ Whh2,
    const float* __restrict__ bih2, const float* __restrict__ bhh2,
    const float* __restrict__ Wfc,  const float* __restrict__ bfc,
    float* __restrict__ out)
{
  __shared__ __align__(16) __bf16 sA1[2][4 * 64 * 8];      // h1 hi(kb0,1)/lo(kb2,3) (8 KB)
  __shared__ __align__(16) __bf16 sA2[2][2 * 64 * 8];      // h2 hi(kb0)/lo(kb1) (4 KB)
  __shared__ __align__(16) __bf16 sW2lo[8 * 2 * 64 * 8];   // W_ih2 LO frags (16 KB)
  __shared__ __align__(16) float  sP[2][2 * 4 * 64 * 4];   // pA partials, ping-pong (16 KB)
  __shared__ __align__(16) float  sH2f[16 * 32];           // final h2 [batch][unit]

  const int tid  = threadIdx.x;
  const int w    = tid >> 6;        // wave 0..7
  const int lane = tid & 63;
  const int q    = lane >> 4;
  const int col  = lane & 15;
  const int b0   = blockIdx.x * NB;

  const bool isL1  = (w < 4);
  const bool isL2b = (w == 4) || (w == 5);
  const bool isL2a = (w >= 6);
  const int  wl2b  = w - 4;
  const int  wl2a  = w - 6;

  if (isL1) __builtin_amdgcn_s_setprio(1);   // serial-chain waves win issue arbitration

  // ---------------- L1 weights into registers ----------------
  bf16x8 bhh[4][4];   // W_hh1 hi(kb0,1)/lo(kb2,3)
  bf16x8 bih[4];      // W_ih1 packed [Wh;Wl]
  f32x4  b1sd[4];     // bias seeds (broadcast f32x4, built once)
  if (isL1) {
#pragma unroll
    for (int g = 0; g < 4; ++g) {
      const int r = g * 64 + w * 16 + col;
      const float* Wr = Whh1 + r * 64;
      bf16x8 h0, l0, h1f, l1f;
      load_frag8(Wr, 0 * 32 + q * 8, h0, l0);
      load_frag8(Wr, 1 * 32 + q * 8, h1f, l1f);
      bhh[g][0] = h0; bhh[g][1] = h1f; bhh[g][2] = l0; bhh[g][3] = l1f;
      bf16x8 xh, xl;
      load_frag8(Wih1 + r * 16, (q & 1) * 8, xh, xl);
      bih[g] = (q < 2) ? xh : xl;
      const float bv = bih1[r] + bhh1[r];
      b1sd[g][0] = bv; b1sd[g][1] = bv; b1sd[g][2] = bv; b1sd[g][3] = bv;
    }
  }
  // ---------------- L2b weights: W_hh2 hi/lo ----------------
  bf16x8 wh2h[4], wh2l[4];
  f32x4  b2sd[4];
  if (isL2b) {
#pragma unroll
    for (int g = 0; g < 4; ++g) {
      const int r = g * 32 + wl2b * 16 + col;
      bf16x8 hh, ll;
      load_frag8(Whh2 + r * 32, q * 8, hh, ll);
      wh2h[g] = hh; wh2l[g] = ll;
      const float bv = bih2[r] + bhh2[r];
      b2sd[g][0] = bv; b2sd[g][1] = bv; b2sd[g][2] = bv; b2sd[g][3] = bv;
    }
  }
  // ---------------- L2a weights: W_ih2 HI ----------------
  bf16x8 w2ih[4][2];
  if (isL2a) {
#pragma unroll
    for (int g = 0; g < 4; ++g) {
      const int r = g * 32 + wl2a * 16 + col;
#pragma unroll
      for (int kb = 0; kb < 2; ++kb) {
        bf16x8 hh, ll;
        load_frag8(Wih2 + r * 64, kb * 32 + q * 8, hh, ll);
        w2ih[g][kb] = hh;
      }
    }
  }

  // ---------------- LDS staging: W_ih2 LO frags ----------------
  for (int idx = tid; idx < 8 * 2 * 64; idx += 512) {
    const int nt  = idx >> 7;
    const int kb2 = (idx >> 6) & 1;
    const int ln  = idx & 63;
    const int qq  = ln >> 4, cc = ln & 15;
    const int g   = nt >> 1, wv = nt & 1;
    const int r   = g * 32 + wv * 16 + cc;
    const int k0  = kb2 * 32 + qq * 8;
    bf16x8 hh, ll;
    load_frag8(Wih2 + r * 64, k0, hh, ll);
    *(bf16x8*)&sW2lo[((nt * 2 + kb2) * 64 + ln) * 8] = ll;
  }

  // ---------------- zero state buffers ----------------
  {
    bf16x8 z;
#pragma unroll
    for (int j = 0; j < 8; ++j) z[j] = (__bf16)0.f;
    for (int i = tid; i < 2 * 4 * 64; i += 512) *(bf16x8*)&sA1[0][i * 8] = z;
    for (int i = tid; i < 2 * 2 * 64; i += 512) *(bf16x8*)&sA2[0][i * 8] = z;
  }
  __syncthreads();

  // x prefetch registers (L1 waves; lane (col,q) owns x[b0+col][t][(q&1)*8 .. +8])
  const float* xbase = x + ((size_t)(b0 + col) * T_SEQ) * 16 + (q & 1) * 8;
  float4 xcA, xcB, xnA, xnB;
  if (isL1) {
    xcA = *(const float4*)(xbase + 0);
    xcB = *(const float4*)(xbase + 4);
  }

  float c1s[4] = {0.f, 0.f, 0.f, 0.f};
  float c2s[4] = {0.f, 0.f, 0.f, 0.f};
  const int uu   = w * 16 + col;
  const int uu2b = wl2b * 16 + col;

  const int kbh  = uu >> 5;
  const int lnb  = ((uu & 31) >> 3) * 16;
  const int jj   = uu & 7;
  const int lnb2 = ((uu2b & 31) >> 3) * 16;
  const int jj2  = uu2b & 7;

  const f32x4 z4 = {0.f, 0.f, 0.f, 0.f};

// One pipeline interval. Pc and DO_* are compile-time literals.
#define STEP(Pc, DO_L1, DO_XPRE, DO_L2A, DO_L2B, DO_H2F, TT) do {              \
    if ((DO_L1) && isL1) {                                                     \
      bf16x8 a1[4];                                                            \
      _Pragma("unroll")                                                        \
      for (int kb = 0; kb < 4; ++kb)                                           \
        a1[kb] = *(const bf16x8*)&sA1[(Pc)][(kb * 64 + lane) * 8];             \
      if (DO_XPRE) {                                                           \
        const float* xr = xbase + (size_t)((TT) + 1) * 16;                     \
        xnA = *(const float4*)(xr + 0);                                        \
        xnB = *(const float4*)(xr + 4);                                        \
      }                                                                        \
      const float xc[8] = {xcA.x, xcA.y, xcA.z, xcA.w, xcB.x, xcB.y, xcB.z, xcB.w}; \
      bf16x8 xh8, xl8;                                                         \
      _Pragma("unroll")                                                        \
      for (int j = 0; j < 8; ++j) {                                            \
        __bf16 h_, l_; split_fast(xc[j], h_, l_);                              \
        xh8[j] = h_; xl8[j] = l_;                                              \
      }                                                                        \
      const bf16x8 ax0 = (q < 2) ? xh8 : xl8;                                  \
      const bf16x8 ax1 = (q < 2) ? xl8 : xh8;                                  \
      f32x4 ca[4], cb[4];                                                      \
      _Pragma("unroll")                                                        \
      for (int g = 0; g < 4; ++g) {                                            \
        ca[g] = MFMA(ax0,   bih[g],    b1sd[g]);                               \
        ca[g] = MFMA(ax1,   bih[g],    ca[g]);                                 \
        ca[g] = MFMA(a1[0], bhh[g][0], ca[g]);                                 \
        ca[g] = MFMA(a1[1], bhh[g][1], ca[g]);                                 \
        cb[g] = MFMA(a1[2], bhh[g][0], z4);                                    \
        cb[g] = MFMA(a1[3], bhh[g][1], cb[g]);                                 \
        cb[g] = MFMA(a1[0], bhh[g][2], cb[g]);                                 \
        cb[g] = MFMA(a1[1], bhh[g][3], cb[g]);                                 \
      }                                                                        \
      _Pragma("unroll")                                                        \
      for (int r = 0; r < 4; ++r) {                                            \
        const float iv = fsig(ca[0][r] + cb[0][r]);                            \
        const float fv = fsig(ca[1][r] + cb[1][r]);                            \
        const float gv = ftanhf(ca[2][r] + cb[2][r]);                          \
        const float ov = fsig(ca[3][r] + cb[3][r]);                            \
        const float cc = fmaf(fv, c1s[r], iv * gv);                            \
        c1s[r] = cc;                                                           \
        __bf16 hh_, hl_;                                                       \
        split_fast(ov * ftanhf(cc), hh_, hl_);                                 \
        const int m = q * 4 + r;                                               \
        sA1[1 - (Pc)][((kbh * 64) + lnb + m) * 8 + jj]       = hh_;            \
        sA1[1 - (Pc)][(((2 + kbh) * 64) + lnb + m) * 8 + jj] = hl_;            \
      }                                                                        \
      if (DO_XPRE) { xcA = xnA; xcB = xnB; }                                   \
    }                                                                          \
    if ((DO_L2A) && isL2a) {                                                   \
      bf16x8 a2[4];                                                            \
      _Pragma("unroll")                                                        \
      for (int kb = 0; kb < 4; ++kb)                                           \
        a2[kb] = *(const bf16x8*)&sA1[(Pc)][(kb * 64 + lane) * 8];             \
      _Pragma("unroll")                                                        \
      for (int g = 0; g < 4; ++g) {                                            \
        const int nt = g * 2 + wl2a;                                           \
        const bf16x8 bb2 = *(const bf16x8*)&sW2lo[((nt * 2 + 0) * 64 + lane) * 8]; \
        const bf16x8 bb3 = *(const bf16x8*)&sW2lo[((nt * 2 + 1) * 64 + lane) * 8]; \
        f32x4 pa;                                                              \
        pa = MFMA(a2[0], w2ih[g][0], z4);    /* hi x hi */                     \
        pa = MFMA(a2[1], w2ih[g][1], pa);                                      \
        pa = MFMA(a2[0], bb2, pa);           /* hi x lo */                     \
        pa = MFMA(a2[1], bb3, pa);                                             \
        pa = MFMA(a2[2], w2ih[g][0], pa);    /* lo x hi */                     \
        pa = MFMA(a2[3], w2ih[g][1], pa);                                      \
        *(f32x4*)&sP[(Pc)][((wl2a * 4 + g) * 64 + lane) * 4] = pa;             \
      }                                                                        \
    }                                                                          \
    if ((DO_L2B) && isL2b) {                                                   \
      const bf16x8 ah0 = *(const bf16x8*)&sA2[1 - (Pc)][(0 * 64 + lane) * 8];  \
      const bf16x8 ah1 = *(const bf16x8*)&sA2[1 - (Pc)][(1 * 64 + lane) * 8];  \
      f32x4 c2[4];                                                             \
      _Pragma("unroll")                                                        \
      for (int g = 0; g < 4; ++g) {                                            \
        c2[g] = MFMA(ah0, wh2h[g], b2sd[g]);                                   \
        c2[g] = MFMA(ah1, wh2h[g], c2[g]);                                     \
        c2[g] = MFMA(ah0, wh2l[g], c2[g]);                                     \
        c2[g] += *(const f32x4*)&sP[1 - (Pc)][((wl2b * 4 + g) * 64 + lane) * 4]; \
      }                                                                        \
      _Pragma("unroll")                                                        \
      for (int r = 0; r < 4; ++r) {                                            \
        const float iv = fsig(c2[0][r]);                                       \
        const float fv = fsig(c2[1][r]);                                       \
        const float gv = ftanhf(c2[2][r]);                                     \
        const float ov = fsig(c2[3][r]);                                       \
        const float cc = fmaf(fv, c2s[r], iv * gv);                            \
        c2s[r] = cc;                                                           \
        const float hf = ov * ftanhf(cc);                                      \
        __bf16 hh_, hl_;                                                       \
        split_fast(hf, hh_, hl_);                                              \
        const int m = q * 4 + r;                                               \
        sA2[(Pc)][((0 * 64) + lnb2 + m) * 8 + jj2] = hh_;                      \
        sA2[(Pc)][((1 * 64) + lnb2 + m) * 8 + jj2] = hl_;                      \
        if (DO_H2F) sH2f[m * 32 + uu2b] = hf;                                  \
      }                                                                        \
    }                                                                          \
    __syncthreads();                                                           \
  } while (0)

  // -------- pipeline fill --------
  STEP(0, true,  true,  false, false, false, 0);
  STEP(1, true,  true,  true,  false, false, 1);
  // -------- steady state --------
  for (int t = 2; t < 166; t += 2) {
    STEP(0, true, true, true, true, false, t);
    STEP(1, true, true, true, true, false, t + 1);
  }
  // -------- drain --------
  STEP(0, true,  true,  true,  true,  false, 166);
  STEP(1, true,  false, true,  true,  false, 167);
  STEP(0, false, false, true,  true,  false, 168);
  STEP(1, false, false, false, true,  true,  169);
#undef STEP

  // ======== FC epilogue ========
  if (tid < NB) {
    float s = bfc[0];
#pragma unroll
    for (int j = 0; j < 32; ++j) s = fmaf(Wfc[j], sH2f[tid * 32 + j], s);
    out[b0 + tid] = s;
  }
}

extern "C" void kernel_launch(void* const* d_in, const int* in_sizes, int n_in,
                              void* d_out, int out_size, void* d_ws, size_t ws_size,
                              hipStream_t stream) {
  (void)in_sizes; (void)n_in; (void)out_size; (void)d_ws; (void)ws_size;
  const float* x    = (const float*)d_in[0];
  const float* Wih1 = (const float*)d_in[1];
  const float* Whh1 = (const float*)d_in[2];
  const float* bih1 = (const float*)d_in[3];
  const float* bhh1 = (const float*)d_in[4];
  const float* Wih2 = (const float*)d_in[5];
  const float* Whh2 = (const float*)d_in[6];
  const float* bih2 = (const float*)d_in[7];
  const float* bhh2 = (const float*)d_in[8];
  const float* Wfc  = (const float*)d_in[9];
  const float* bfc  = (const float*)d_in[10];
  float* out = (float*)d_out;

  hipLaunchKernelGGL(lstm_mfma_kernel, dim3(4096 / NB), dim3(512), 0, stream,
                     x, Wih1, Whh1, bih1, bhh1, Wih2, Whh2, bih2, bhh2, Wfc, bfc, out);
}